// Round 5
// baseline (746.445 us; speedup 1.0000x reference)
//
#include <hip/hip_runtime.h>

typedef unsigned short u16;
typedef unsigned int   u32;
typedef __bf16 bf16x8 __attribute__((ext_vector_type(8)));
typedef float  f32x4  __attribute__((ext_vector_type(4)));
typedef float  f32x16 __attribute__((ext_vector_type(16)));

__device__ __forceinline__ u16 f2bf(float f){
  u32 u = __float_as_uint(f);
  u32 r = (u + 0x7FFFu + ((u >> 16) & 1u)) >> 16;   // RNE
  return (u16)r;
}

// ---------------------------------------------------------------------------
// Pass 1: row sums of A (f32) fused with A -> bf16 conversion (unscaled).
// ---------------------------------------------------------------------------
__global__ __launch_bounds__(256) void rowsum_convert(
    const float* __restrict__ A, u16* __restrict__ Ab, float* __restrict__ ds){
  const int row = blockIdx.x, t = threadIdx.x;
  const float* ar = A + (size_t)row * 8192;
  u16* br = Ab + (size_t)row * 8192;
  float s = 0.f;
  #pragma unroll
  for (int j = 0; j < 8; ++j){
    int c = j * 256 + t;                    // float4 index, coalesced
    float4 v = ((const float4*)ar)[c];
    s += (v.x + v.y) + (v.z + v.w);
    ushort4 o;
    o.x = f2bf(v.x); o.y = f2bf(v.y); o.z = f2bf(v.z); o.w = f2bf(v.w);
    ((ushort4*)br)[c] = o;
  }
  #pragma unroll
  for (int off = 32; off > 0; off >>= 1) s += __shfl_down(s, off, 64);
  __shared__ float red[4];
  if ((t & 63) == 0) red[t >> 6] = s;
  __syncthreads();
  if (t == 0) ds[row] = rsqrtf(red[0] + red[1] + red[2] + red[3]);
}

// ---------------------------------------------------------------------------
// Small feature GEMM: Vt[o][i] = bf16( ds[i] * sum_k in[i][k] * W[k][o] )
// ---------------------------------------------------------------------------
template<int K, int F, bool INBF16>
__global__ __launch_bounds__(256) void small_gemm(
    const void* __restrict__ inp, const float* __restrict__ W,
    const float* __restrict__ ds, u16* __restrict__ Vt){
  constexpr int G   = 256 / F;     // 1 (F=256) or 2 (F=128)
  constexpr int RPB = 16 * G;      // rows per block
  __shared__ float xs[RPB * K];
  const int t  = threadIdx.x;
  const int r0 = blockIdx.x * RPB;
  if constexpr (INBF16){
    const u16* ip = (const u16*)inp + (size_t)r0 * K;
    constexpr int IT = (RPB * K) / (256 * 8);
    #pragma unroll
    for (int j = 0; j < IT; ++j){
      int c = j * 256 + t;
      uint4 v = ((const uint4*)ip)[c];
      float* xp = xs + c * 8;
      xp[0] = __uint_as_float((v.x & 0xFFFFu) << 16);
      xp[1] = __uint_as_float(v.x & 0xFFFF0000u);
      xp[2] = __uint_as_float((v.y & 0xFFFFu) << 16);
      xp[3] = __uint_as_float(v.y & 0xFFFF0000u);
      xp[4] = __uint_as_float((v.z & 0xFFFFu) << 16);
      xp[5] = __uint_as_float(v.z & 0xFFFF0000u);
      xp[6] = __uint_as_float((v.w & 0xFFFFu) << 16);
      xp[7] = __uint_as_float(v.w & 0xFFFF0000u);
    }
  } else {
    const float* ip = (const float*)inp + (size_t)r0 * K;
    constexpr int IT = (RPB * K) / (256 * 4);
    #pragma unroll
    for (int j = 0; j < IT; ++j){
      int c = j * 256 + t;
      ((float4*)xs)[c] = ((const float4*)ip)[c];
    }
  }
  __syncthreads();
  const int o = t % F, g = t / F;
  float acc[16];
  #pragma unroll
  for (int r = 0; r < 16; ++r) acc[r] = 0.f;
  const float* xr = xs + g * 16 * K;
  for (int k = 0; k < K; k += 4){
    float w0 = W[(k+0)*F + o];
    float w1 = W[(k+1)*F + o];
    float w2 = W[(k+2)*F + o];
    float w3 = W[(k+3)*F + o];
    #pragma unroll
    for (int r = 0; r < 16; ++r){
      float4 xv = *(const float4*)(xr + r*K + k);
      acc[r] += xv.x*w0 + xv.y*w1 + xv.z*w2 + xv.w*w3;
    }
  }
  const int rb = r0 + g * 16;
  union { u16 u[16]; uint4 v[2]; } pk;
  #pragma unroll
  for (int r = 0; r < 16; ++r) pk.u[r] = f2bf(acc[r] * ds[rb + r]);
  uint4* dst = (uint4*)(Vt + (size_t)o * 8192 + rb);
  dst[0] = pk.v[0];
  dst[1] = pk.v[1];
}

// ---------------------------------------------------------------------------
// Big GEMM: in-block K-split, register-direct K-loop (no barriers), LDS tree
// reduction at the end only.  out[i][o] = ds[i]*sum_j Ab[i][j]*Vt[o][j]
//
// 256 blocks x 1024 threads = 16 waves = 4 K-splits x 4 col-groups.
// Block = 32 rows x F cols (A read ONCE per GEMM; B L2-resident).
// Wave = 32 x F/4 via mfma_f32_32x32x16_bf16; depth-4 register prefetch,
// ENFORCED with sched_group_barrier (T19): hipcc otherwise sinks the
// prefetch loads to their uses (R4: VGPR_Count=44 proved the pipeline was
// deleted -> every MFMA ate full L2 latency, MfmaUtil 6%).
// Per unrolled step the region is {1+CT VMEM_READ (for kt+D), CT MFMA (kt)}:
// no intra-region dependency, so auto-waitcnt stays counted (never 0).
// ---------------------------------------------------------------------------
template<int F, bool RELU, bool OUTF32>
__global__ __launch_bounds__(1024, 4) void gemm_tree(
    const u16* __restrict__ Ab, const u16* __restrict__ Vt,
    const float* __restrict__ ds, u16* __restrict__ Hout, float* __restrict__ Fout){
  constexpr int CT  = F / 128;          // 32-col tiles per wave (2 or 1)
  constexpr int NKT = 2048 / 16;        // 128 K-16 steps per K-split
  constexpr int D   = 4;                // prefetch depth (steps)
  __shared__ float red[2][32][F];       // 64 KB (F=256) / 32 KB (F=128)

  const int t = threadIdx.x, wave = t >> 6, lane = t & 63;
  const int ks = wave >> 2;             // K-split 0..3
  const int cg = wave & 3;              // col-group 0..3
  const int row0 = blockIdx.x * 32;
  const int colb = cg * (F / 4);
  const int kbase = ks * 2048 + ((lane >> 5) << 3);

  const u16* ap = Ab + (size_t)(row0 + (lane & 31)) * 8192 + kbase;
  const u16* bp[CT];
  #pragma unroll
  for (int ct = 0; ct < CT; ++ct)
    bp[ct] = Vt + (size_t)(colb + ct * 32 + (lane & 31)) * 8192 + kbase;

  f32x16 acc[CT];
  #pragma unroll
  for (int ct = 0; ct < CT; ++ct)
    #pragma unroll
    for (int i = 0; i < 16; ++i) acc[ct][i] = 0.f;

  bf16x8 aQ[D], bQ[D][CT];
  #pragma unroll
  for (int d = 0; d < D; ++d){
    aQ[d] = *(const bf16x8*)(const void*)(ap + d * 16);
    #pragma unroll
    for (int ct = 0; ct < CT; ++ct)
      bQ[d][ct] = *(const bf16x8*)(const void*)(bp[ct] + d * 16);
  }
  for (int kt = 0; kt < NKT - D; kt += D){
    #pragma unroll
    for (int u = 0; u < D; ++u){
      bf16x8 a = aQ[u];
      bf16x8 b[CT];
      #pragma unroll
      for (int ct = 0; ct < CT; ++ct) b[ct] = bQ[u][ct];
      // prefetch for step kt+u+D (independent of this step's MFMAs)
      aQ[u] = *(const bf16x8*)(const void*)(ap + (kt + u + D) * 16);
      #pragma unroll
      for (int ct = 0; ct < CT; ++ct)
        bQ[u][ct] = *(const bf16x8*)(const void*)(bp[ct] + (kt + u + D) * 16);
      #pragma unroll
      for (int ct = 0; ct < CT; ++ct)
        acc[ct] = __builtin_amdgcn_mfma_f32_32x32x16_bf16(a, b[ct], acc[ct], 0, 0, 0);
      // pin the schedule: loads stay D steps ahead of their consumers
      __builtin_amdgcn_sched_group_barrier(0x020, 1 + CT, 0);  // VMEM_READ
      __builtin_amdgcn_sched_group_barrier(0x008, CT, 0);      // MFMA
    }
  }
  #pragma unroll
  for (int u = 0; u < D; ++u)
    #pragma unroll
    for (int ct = 0; ct < CT; ++ct)
      acc[ct] = __builtin_amdgcn_mfma_f32_32x32x16_bf16(aQ[u], bQ[u][ct], acc[ct], 0, 0, 0);

  // ---- K-split tree reduction: ((ks0+ks2)+(ks1+ks3)), 3 barriers total ----
  // C/D layout (m74/m101): col = lane&31, row = (r&3) + 8*(r>>2) + 4*(lane>>5)
  const int rhi = (lane >> 5) << 2;
  const int cl  = lane & 31;
  if (ks >= 2){                          // ks2 -> red[0], ks3 -> red[1]
    #pragma unroll
    for (int ct = 0; ct < CT; ++ct)
      #pragma unroll
      for (int r = 0; r < 16; ++r)
        red[ks - 2][(r & 3) + ((r >> 2) << 3) + rhi][colb + ct * 32 + cl] = acc[ct][r];
  }
  __syncthreads();
  if (ks < 2){                           // ks0 += red[0], ks1 += red[1]
    #pragma unroll
    for (int ct = 0; ct < CT; ++ct)
      #pragma unroll
      for (int r = 0; r < 16; ++r)
        acc[ct][r] += red[ks][(r & 3) + ((r >> 2) << 3) + rhi][colb + ct * 32 + cl];
  }
  __syncthreads();
  if (ks == 1){                          // ks1 -> red[0]
    #pragma unroll
    for (int ct = 0; ct < CT; ++ct)
      #pragma unroll
      for (int r = 0; r < 16; ++r)
        red[0][(r & 3) + ((r >> 2) << 3) + rhi][colb + ct * 32 + cl] = acc[ct][r];
  }
  __syncthreads();
  if (ks == 0){                          // final: += , scale, (relu), store
    #pragma unroll
    for (int ct = 0; ct < CT; ++ct){
      #pragma unroll
      for (int r = 0; r < 16; ++r){
        const int rl = (r & 3) + ((r >> 2) << 3) + rhi;
        float v = acc[ct][r] + red[0][rl][colb + ct * 32 + cl];
        const int row = row0 + rl;
        v *= ds[row];
        if (RELU) v = fmaxf(v, 0.f);
        const int col = colb + ct * 32 + cl;
        if (OUTF32) Fout[(size_t)row * F + col] = v;
        else        Hout[(size_t)row * F + col] = f2bf(v);
      }
    }
  }
}

// ---------------------------------------------------------------------------
// Attention scores: sc[i] = tanh(Z[i,:] @ Wl^T + bl) @ q + b
// ---------------------------------------------------------------------------
__device__ __forceinline__ float tanh_fast(float x){
  x = fminf(fmaxf(x, -15.f), 15.f);
  float e = __expf(2.f * x);
  return (e - 1.f) / (e + 1.f);
}

__global__ __launch_bounds__(256) void attn_scores(
    const float* __restrict__ Z, const float* __restrict__ Wl,
    const float* __restrict__ bl, const float* __restrict__ q,
    const float* __restrict__ bsc, float* __restrict__ sc){
  __shared__ float wl[128 * 128];          // 64 KiB exactly, swizzled
  const int t = threadIdx.x, lane = t & 63, wave = t >> 6;
  for (int j = 0; j < 64; ++j){
    int idx = j * 256 + t;
    int o = idx >> 7, k = idx & 127;
    int c = k >> 2, e = k & 3;
    wl[o * 128 + (((c ^ (o & 31)) << 2) | e)] = Wl[idx];
  }
  __syncthreads();
  const float bl0 = bl[lane], bl1 = bl[lane + 64];
  const float q0  = q[lane],  q1  = q[lane + 64];
  const float bb  = bsc[0];
  const int r0 = blockIdx.x * 16;
  for (int rr = 0; rr < 4; ++rr){
    int r = r0 + wave * 4 + rr;
    float d0 = 0.f, d1 = 0.f;
    #pragma unroll
    for (int c = 0; c < 32; ++c){
      float4 zv = *(const float4*)(Z + (size_t)r * 128 + c * 4);
      float4 w0 = *(const float4*)&wl[ lane      * 128 + ((c ^ (lane & 31)) << 2)];
      float4 w1 = *(const float4*)&wl[(lane + 64)* 128 + ((c ^ (lane & 31)) << 2)];
      d0 += zv.x*w0.x + zv.y*w0.y + zv.z*w0.z + zv.w*w0.w;
      d1 += zv.x*w1.x + zv.y*w1.y + zv.z*w1.z + zv.w*w1.w;
    }
    float s = tanh_fast(d0 + bl0) * q0 + tanh_fast(d1 + bl1) * q1;
    #pragma unroll
    for (int off = 32; off > 0; off >>= 1) s += __shfl_down(s, off, 64);
    if (lane == 0) sc[r] = s + bb;
  }
}

__global__ __launch_bounds__(1024) void softmax_red(
    const float* __restrict__ sc, float* __restrict__ sred){
  const int t = threadIdx.x, lane = t & 63, wave = t >> 6;
  __shared__ float red[16];
  float m = -1e30f;
  for (int i = t; i < 8192; i += 1024) m = fmaxf(m, sc[i]);
  #pragma unroll
  for (int off = 32; off > 0; off >>= 1) m = fmaxf(m, __shfl_down(m, off, 64));
  if (lane == 0) red[wave] = m;
  __syncthreads();
  if (t == 0){
    float mm = red[0];
    for (int w = 1; w < 16; ++w) mm = fmaxf(mm, red[w]);
    red[0] = mm;
  }
  __syncthreads();
  const float bmax = red[0];
  __syncthreads();
  float s = 0.f;
  for (int i = t; i < 8192; i += 1024) s += __expf(sc[i] - bmax);
  #pragma unroll
  for (int off = 32; off > 0; off >>= 1) s += __shfl_down(s, off, 64);
  if (lane == 0) red[wave] = s;
  __syncthreads();
  if (t == 0){
    float ss = 0.f;
    for (int w = 0; w < 16; ++w) ss += red[w];
    sred[0] = bmax; sred[1] = ss;
  }
}

__global__ __launch_bounds__(256) void weighted_part(
    const float* __restrict__ sc, const float* __restrict__ sred,
    const float* __restrict__ Z, float* __restrict__ part){
  const int blk = blockIdx.x, t = threadIdx.x;
  const int o = t & 127, h = t >> 7;
  const float bmax = sred[0], inv = 1.f / sred[1];
  float acc = 0.f;
  const int i0 = blk * 128;
  for (int i = i0 + h; i < i0 + 128; i += 2){
    float w = __expf(sc[i] - bmax) * inv;
    acc += w * Z[(size_t)i * 128 + o];
  }
  __shared__ float l[256];
  l[t] = acc;
  __syncthreads();
  if (h == 0) part[blk * 128 + o] = l[o] + l[o + 128];
}

__global__ __launch_bounds__(128) void final_red(
    const float* __restrict__ part, float* __restrict__ out){
  const int o = threadIdx.x;
  float s = 0.f;
  for (int b = 0; b < 64; ++b) s += part[b * 128 + o];
  out[o] = s;
}

// ---------------------------------------------------------------------------
extern "C" void kernel_launch(void* const* d_in, const int* in_sizes, int n_in,
                              void* d_out, int out_size, void* d_ws, size_t ws_size,
                              hipStream_t stream){
  const float* x  = (const float*)d_in[0];
  const float* A  = (const float*)d_in[1];
  const float* W1 = (const float*)d_in[2];
  const float* W2 = (const float*)d_in[3];
  const float* W3 = (const float*)d_in[4];
  const float* Wl = (const float*)d_in[5];
  const float* bl = (const float*)d_in[6];
  const float* q  = (const float*)d_in[7];
  const float* b  = (const float*)d_in[8];
  float* out = (float*)d_out;
  char* ws = (char*)d_ws;

  u16*   AB   = (u16*)(ws);                      // 128 MiB
  float* DS   = (float*)(ws + 134217728);        // 32 KiB
  u16*   VT   = (u16*)(ws + 134250496);          // 4 MiB [F][8192]
  u16*   HB   = (u16*)(ws + 138444800);          // 4 MiB [8192][256]
  float* SC   = (float*)(ws + 142639104);        // 8192 f32 scores
  float* SP   = (float*)(ws + 142671872);        // 64*128 f32
  float* SRED = (float*)(ws + 142704640);        // {max, sumexp}

  rowsum_convert<<<8192, 256, 0, stream>>>(A, AB, DS);
  // layer 1
  small_gemm<128, 256, false><<<512, 256, 0, stream>>>(x, W1, DS, VT);
  gemm_tree<256, true, false><<<256, 1024, 0, stream>>>(AB, VT, DS, HB, nullptr);
  // layer 2
  small_gemm<256, 256, true><<<512, 256, 0, stream>>>(HB, W2, DS, VT);
  gemm_tree<256, true, false><<<256, 1024, 0, stream>>>(AB, VT, DS, HB, nullptr);
  // layer 3 -> z_context f32 straight into d_out
  small_gemm<256, 128, true><<<256, 256, 0, stream>>>(HB, W3, DS, VT);
  gemm_tree<128, false, true><<<256, 1024, 0, stream>>>(AB, VT, DS, nullptr, out);
  // attention pooling
  attn_scores<<<512, 256, 0, stream>>>(out, Wl, bl, q, b, SC);
  softmax_red<<<1, 1024, 0, stream>>>(SC, SRED);
  weighted_part<<<64, 256, 0, stream>>>(SC, SRED, out, SP);
  final_red<<<1, 128, 0, stream>>>(SP, out + 8192 * 128);
}

// Round 7
// 734.785 us; speedup vs baseline: 1.0159x; 1.0159x over previous
//
#include <hip/hip_runtime.h>

typedef unsigned short u16;
typedef unsigned int   u32;
typedef __bf16 bf16x8 __attribute__((ext_vector_type(8)));
typedef float  f32x4  __attribute__((ext_vector_type(4)));
typedef float  f32x16 __attribute__((ext_vector_type(16)));

__device__ __forceinline__ u16 f2bf(float f){
  u32 u = __float_as_uint(f);
  u32 r = (u + 0x7FFFu + ((u >> 16) & 1u)) >> 16;   // RNE
  return (u16)r;
}

// Inline-asm load: opaque to hipcc's waitcnt/scheduling, so the prefetch
// pipeline SURVIVES (R4/R5: C-level loads got sunk to their uses -> serial
// full-latency round trips per step). "=&v" early-clobber: the delayed-write
// destination must NOT alias the address register pair (R6 NaN cause #2).
#define GLD(dst, p, OFF) \
  asm volatile("global_load_dwordx4 %0, %1, off offset:" OFF \
               : "=&v"(dst) : "v"(p))
// Counted wait (never 0 in the loop) + rule-18 fence so MFMAs can't hoist
// above the wait.
#define WAITV(N) do { \
    asm volatile("s_waitcnt vmcnt(" N ")"); \
    __builtin_amdgcn_sched_barrier(0); \
  } while (0)

// ---------------------------------------------------------------------------
// Pass 1: row sums of A (f32) fused with A -> bf16 conversion (unscaled).
// ---------------------------------------------------------------------------
__global__ __launch_bounds__(256) void rowsum_convert(
    const float* __restrict__ A, u16* __restrict__ Ab, float* __restrict__ ds){
  const int row = blockIdx.x, t = threadIdx.x;
  const float* ar = A + (size_t)row * 8192;
  u16* br = Ab + (size_t)row * 8192;
  float s = 0.f;
  #pragma unroll
  for (int j = 0; j < 8; ++j){
    int c = j * 256 + t;                    // float4 index, coalesced
    float4 v = ((const float4*)ar)[c];
    s += (v.x + v.y) + (v.z + v.w);
    ushort4 o;
    o.x = f2bf(v.x); o.y = f2bf(v.y); o.z = f2bf(v.z); o.w = f2bf(v.w);
    ((ushort4*)br)[c] = o;
  }
  #pragma unroll
  for (int off = 32; off > 0; off >>= 1) s += __shfl_down(s, off, 64);
  __shared__ float red[4];
  if ((t & 63) == 0) red[t >> 6] = s;
  __syncthreads();
  if (t == 0) ds[row] = rsqrtf(red[0] + red[1] + red[2] + red[3]);
}

// ---------------------------------------------------------------------------
// Small feature GEMM: Vt[o][i] = bf16( ds[i] * sum_k in[i][k] * W[k][o] )
// ---------------------------------------------------------------------------
template<int K, int F, bool INBF16>
__global__ __launch_bounds__(256) void small_gemm(
    const void* __restrict__ inp, const float* __restrict__ W,
    const float* __restrict__ ds, u16* __restrict__ Vt){
  constexpr int G   = 256 / F;     // 1 (F=256) or 2 (F=128)
  constexpr int RPB = 16 * G;      // rows per block
  __shared__ float xs[RPB * K];
  const int t  = threadIdx.x;
  const int r0 = blockIdx.x * RPB;
  if constexpr (INBF16){
    const u16* ip = (const u16*)inp + (size_t)r0 * K;
    constexpr int IT = (RPB * K) / (256 * 8);
    #pragma unroll
    for (int j = 0; j < IT; ++j){
      int c = j * 256 + t;
      uint4 v = ((const uint4*)ip)[c];
      float* xp = xs + c * 8;
      xp[0] = __uint_as_float((v.x & 0xFFFFu) << 16);
      xp[1] = __uint_as_float(v.x & 0xFFFF0000u);
      xp[2] = __uint_as_float((v.y & 0xFFFFu) << 16);
      xp[3] = __uint_as_float(v.y & 0xFFFF0000u);
      xp[4] = __uint_as_float((v.z & 0xFFFFu) << 16);
      xp[5] = __uint_as_float(v.z & 0xFFFF0000u);
      xp[6] = __uint_as_float((v.w & 0xFFFFu) << 16);
      xp[7] = __uint_as_float(v.w & 0xFFFF0000u);
    }
  } else {
    const float* ip = (const float*)inp + (size_t)r0 * K;
    constexpr int IT = (RPB * K) / (256 * 4);
    #pragma unroll
    for (int j = 0; j < IT; ++j){
      int c = j * 256 + t;
      ((float4*)xs)[c] = ((const float4*)ip)[c];
    }
  }
  __syncthreads();
  const int o = t % F, g = t / F;
  float acc[16];
  #pragma unroll
  for (int r = 0; r < 16; ++r) acc[r] = 0.f;
  const float* xr = xs + g * 16 * K;
  for (int k = 0; k < K; k += 4){
    float w0 = W[(k+0)*F + o];
    float w1 = W[(k+1)*F + o];
    float w2 = W[(k+2)*F + o];
    float w3 = W[(k+3)*F + o];
    #pragma unroll
    for (int r = 0; r < 16; ++r){
      float4 xv = *(const float4*)(xr + r*K + k);
      acc[r] += xv.x*w0 + xv.y*w1 + xv.z*w2 + xv.w*w3;
    }
  }
  const int rb = r0 + g * 16;
  union { u16 u[16]; uint4 v[2]; } pk;
  #pragma unroll
  for (int r = 0; r < 16; ++r) pk.u[r] = f2bf(acc[r] * ds[rb + r]);
  uint4* dst = (uint4*)(Vt + (size_t)o * 8192 + rb);
  dst[0] = pk.v[0];
  dst[1] = pk.v[1];
}

// ---------------------------------------------------------------------------
// Big GEMM: in-block K-split, inline-asm pipelined K-loop, LDS tree reduce.
// out[i][o] = ds[i]*sum_j Ab[i][j]*Vt[o][j]
//
// 256 blocks x 1024 threads = 16 waves = 4 K-splits x 4 col-groups.
// Block = 32 rows x F cols (A read ONCE per GEMM; B L2-resident).
// K-loop: depth-4 asm prefetch (12 loads in flight for CT=2), counted
// s_waitcnt vmcnt(9) (never 0 in loop), sched_barrier(0) after each wait.
// K-STRIDE (R6 fix): one 32x32x16 MFMA step = 16 u16 elements = 32 BYTES;
// 4-step group = 64 elements. Offsets {0,32,64,96}B, advance +64 elem/iter
// (matches R4's verified C addressing ap + kt*16 elements).
// ---------------------------------------------------------------------------
template<int F, bool RELU, bool OUTF32>
__global__ __launch_bounds__(1024, 4) void gemm_pipe(
    const u16* __restrict__ Ab, const u16* __restrict__ Vt,
    const float* __restrict__ ds, u16* __restrict__ Hout, float* __restrict__ Fout){
  constexpr int CT  = F / 128;          // 32-col tiles per wave (2 or 1)
  __shared__ float red[2][32][F];       // 64 KB (F=256) / 32 KB (F=128)

  const int t = threadIdx.x, wave = t >> 6, lane = t & 63;
  const int ks = wave >> 2;             // K-split 0..3
  const int cg = wave & 3;              // col-group 0..3
  const int row0 = blockIdx.x * 32;
  const int colb = cg * (F / 4);
  const int kbase = ks * 2048 + ((lane >> 5) << 3);

  const u16* pa = Ab + (size_t)(row0 + (lane & 31)) * 8192 + kbase;

  f32x16 acc0, acc1;
  #pragma unroll
  for (int i = 0; i < 16; ++i){ acc0[i] = 0.f; acc1[i] = 0.f; }

  if constexpr (CT == 2){
    const u16* pb0 = Vt + (size_t)(colb      + (lane & 31)) * 8192 + kbase;
    const u16* pb1 = Vt + (size_t)(colb + 32 + (lane & 31)) * 8192 + kbase;
    bf16x8 aQ[4], b0Q[4], b1Q[4];
    // prologue: steps 0..3 (12 loads outstanding)
    GLD(aQ[0],pa,"0");  GLD(b0Q[0],pb0,"0");  GLD(b1Q[0],pb1,"0");
    GLD(aQ[1],pa,"32"); GLD(b0Q[1],pb0,"32"); GLD(b1Q[1],pb1,"32");
    GLD(aQ[2],pa,"64"); GLD(b0Q[2],pb0,"64"); GLD(b1Q[2],pb1,"64");
    GLD(aQ[3],pa,"96"); GLD(b0Q[3],pb0,"96"); GLD(b1Q[3],pb1,"96");
    pa += 64; pb0 += 64; pb1 += 64;
    #define STEP2(U, OFF) \
      WAITV("9"); \
      acc0 = __builtin_amdgcn_mfma_f32_32x32x16_bf16(aQ[U], b0Q[U], acc0, 0, 0, 0); \
      acc1 = __builtin_amdgcn_mfma_f32_32x32x16_bf16(aQ[U], b1Q[U], acc1, 0, 0, 0); \
      GLD(aQ[U],pa,OFF); GLD(b0Q[U],pb0,OFF); GLD(b1Q[U],pb1,OFF)
    for (int it = 0; it < 31; ++it){     // consumes steps 0..123
      STEP2(0, "0");
      STEP2(1, "32");
      STEP2(2, "64");
      STEP2(3, "96");
      pa += 64; pb0 += 64; pb1 += 64;
    }
    #undef STEP2
    // epilogue: drain steps 124..127
    WAITV("9");
    acc0 = __builtin_amdgcn_mfma_f32_32x32x16_bf16(aQ[0], b0Q[0], acc0, 0, 0, 0);
    acc1 = __builtin_amdgcn_mfma_f32_32x32x16_bf16(aQ[0], b1Q[0], acc1, 0, 0, 0);
    WAITV("6");
    acc0 = __builtin_amdgcn_mfma_f32_32x32x16_bf16(aQ[1], b0Q[1], acc0, 0, 0, 0);
    acc1 = __builtin_amdgcn_mfma_f32_32x32x16_bf16(aQ[1], b1Q[1], acc1, 0, 0, 0);
    WAITV("3");
    acc0 = __builtin_amdgcn_mfma_f32_32x32x16_bf16(aQ[2], b0Q[2], acc0, 0, 0, 0);
    acc1 = __builtin_amdgcn_mfma_f32_32x32x16_bf16(aQ[2], b1Q[2], acc1, 0, 0, 0);
    WAITV("0");
    acc0 = __builtin_amdgcn_mfma_f32_32x32x16_bf16(aQ[3], b0Q[3], acc0, 0, 0, 0);
    acc1 = __builtin_amdgcn_mfma_f32_32x32x16_bf16(aQ[3], b1Q[3], acc1, 0, 0, 0);
  } else {
    const u16* pb0 = Vt + (size_t)(colb + (lane & 31)) * 8192 + kbase;
    bf16x8 aQ[4], b0Q[4];
    GLD(aQ[0],pa,"0");  GLD(b0Q[0],pb0,"0");
    GLD(aQ[1],pa,"32"); GLD(b0Q[1],pb0,"32");
    GLD(aQ[2],pa,"64"); GLD(b0Q[2],pb0,"64");
    GLD(aQ[3],pa,"96"); GLD(b0Q[3],pb0,"96");
    pa += 64; pb0 += 64;
    #define STEP1(U, OFF) \
      WAITV("6"); \
      acc0 = __builtin_amdgcn_mfma_f32_32x32x16_bf16(aQ[U], b0Q[U], acc0, 0, 0, 0); \
      GLD(aQ[U],pa,OFF); GLD(b0Q[U],pb0,OFF)
    for (int it = 0; it < 31; ++it){
      STEP1(0, "0");
      STEP1(1, "32");
      STEP1(2, "64");
      STEP1(3, "96");
      pa += 64; pb0 += 64;
    }
    #undef STEP1
    WAITV("6");
    acc0 = __builtin_amdgcn_mfma_f32_32x32x16_bf16(aQ[0], b0Q[0], acc0, 0, 0, 0);
    WAITV("4");
    acc0 = __builtin_amdgcn_mfma_f32_32x32x16_bf16(aQ[1], b0Q[1], acc0, 0, 0, 0);
    WAITV("2");
    acc0 = __builtin_amdgcn_mfma_f32_32x32x16_bf16(aQ[2], b0Q[2], acc0, 0, 0, 0);
    WAITV("0");
    acc0 = __builtin_amdgcn_mfma_f32_32x32x16_bf16(aQ[3], b0Q[3], acc0, 0, 0, 0);
  }

  // ---- K-split tree reduction: ((ks0+ks2)+(ks1+ks3)), 3 barriers total ----
  // C/D layout (m74/m101): col = lane&31, row = (r&3) + 8*(r>>2) + 4*(lane>>5)
  const int rhi = (lane >> 5) << 2;
  const int cl  = lane & 31;
  f32x16 accv[2];
  accv[0] = acc0; accv[1] = acc1;
  if (ks >= 2){                          // ks2 -> red[0], ks3 -> red[1]
    #pragma unroll
    for (int ct = 0; ct < CT; ++ct)
      #pragma unroll
      for (int r = 0; r < 16; ++r)
        red[ks - 2][(r & 3) + ((r >> 2) << 3) + rhi][colb + ct * 32 + cl] = accv[ct][r];
  }
  __syncthreads();
  if (ks < 2){                           // ks0 += red[0], ks1 += red[1]
    #pragma unroll
    for (int ct = 0; ct < CT; ++ct)
      #pragma unroll
      for (int r = 0; r < 16; ++r)
        accv[ct][r] += red[ks][(r & 3) + ((r >> 2) << 3) + rhi][colb + ct * 32 + cl];
  }
  __syncthreads();
  if (ks == 1){                          // ks1 -> red[0]
    #pragma unroll
    for (int ct = 0; ct < CT; ++ct)
      #pragma unroll
      for (int r = 0; r < 16; ++r)
        red[0][(r & 3) + ((r >> 2) << 3) + rhi][colb + ct * 32 + cl] = accv[ct][r];
  }
  __syncthreads();
  if (ks == 0){                          // final: += , scale, (relu), store
    #pragma unroll
    for (int ct = 0; ct < CT; ++ct){
      #pragma unroll
      for (int r = 0; r < 16; ++r){
        const int rl = (r & 3) + ((r >> 2) << 3) + rhi;
        float v = accv[ct][r] + red[0][rl][colb + ct * 32 + cl];
        const int row = row0 + rl;
        v *= ds[row];
        if (RELU) v = fmaxf(v, 0.f);
        const int col = colb + ct * 32 + cl;
        if (OUTF32) Fout[(size_t)row * F + col] = v;
        else        Hout[(size_t)row * F + col] = f2bf(v);
      }
    }
  }
}

// ---------------------------------------------------------------------------
// Attention scores: sc[i] = tanh(Z[i,:] @ Wl^T + bl) @ q + b
// ---------------------------------------------------------------------------
__device__ __forceinline__ float tanh_fast(float x){
  x = fminf(fmaxf(x, -15.f), 15.f);
  float e = __expf(2.f * x);
  return (e - 1.f) / (e + 1.f);
}

__global__ __launch_bounds__(256) void attn_scores(
    const float* __restrict__ Z, const float* __restrict__ Wl,
    const float* __restrict__ bl, const float* __restrict__ q,
    const float* __restrict__ bsc, float* __restrict__ sc){
  __shared__ float wl[128 * 128];          // 64 KiB exactly, swizzled
  const int t = threadIdx.x, lane = t & 63, wave = t >> 6;
  for (int j = 0; j < 64; ++j){
    int idx = j * 256 + t;
    int o = idx >> 7, k = idx & 127;
    int c = k >> 2, e = k & 3;
    wl[o * 128 + (((c ^ (o & 31)) << 2) | e)] = Wl[idx];
  }
  __syncthreads();
  const float bl0 = bl[lane], bl1 = bl[lane + 64];
  const float q0  = q[lane],  q1  = q[lane + 64];
  const float bb  = bsc[0];
  const int r0 = blockIdx.x * 16;
  for (int rr = 0; rr < 4; ++rr){
    int r = r0 + wave * 4 + rr;
    float d0 = 0.f, d1 = 0.f;
    #pragma unroll
    for (int c = 0; c < 32; ++c){
      float4 zv = *(const float4*)(Z + (size_t)r * 128 + c * 4);
      float4 w0 = *(const float4*)&wl[ lane      * 128 + ((c ^ (lane & 31)) << 2)];
      float4 w1 = *(const float4*)&wl[(lane + 64)* 128 + ((c ^ (lane & 31)) << 2)];
      d0 += zv.x*w0.x + zv.y*w0.y + zv.z*w0.z + zv.w*w0.w;
      d1 += zv.x*w1.x + zv.y*w1.y + zv.z*w1.z + zv.w*w1.w;
    }
    float s = tanh_fast(d0 + bl0) * q0 + tanh_fast(d1 + bl1) * q1;
    #pragma unroll
    for (int off = 32; off > 0; off >>= 1) s += __shfl_down(s, off, 64);
    if (lane == 0) sc[r] = s + bb;
  }
}

__global__ __launch_bounds__(1024) void softmax_red(
    const float* __restrict__ sc, float* __restrict__ sred){
  const int t = threadIdx.x, lane = t & 63, wave = t >> 6;
  __shared__ float red[16];
  float m = -1e30f;
  for (int i = t; i < 8192; i += 1024) m = fmaxf(m, sc[i]);
  #pragma unroll
  for (int off = 32; off > 0; off >>= 1) m = fmaxf(m, __shfl_down(m, off, 64));
  if (lane == 0) red[wave] = m;
  __syncthreads();
  if (t == 0){
    float mm = red[0];
    for (int w = 1; w < 16; ++w) mm = fmaxf(mm, red[w]);
    red[0] = mm;
  }
  __syncthreads();
  const float bmax = red[0];
  __syncthreads();
  float s = 0.f;
  for (int i = t; i < 8192; i += 1024) s += __expf(sc[i] - bmax);
  #pragma unroll
  for (int off = 32; off > 0; off >>= 1) s += __shfl_down(s, off, 64);
  if (lane == 0) red[wave] = s;
  __syncthreads();
  if (t == 0){
    float ss = 0.f;
    for (int w = 0; w < 16; ++w) ss += red[w];
    sred[0] = bmax; sred[1] = ss;
  }
}

__global__ __launch_bounds__(256) void weighted_part(
    const float* __restrict__ sc, const float* __restrict__ sred,
    const float* __restrict__ Z, float* __restrict__ part){
  const int blk = blockIdx.x, t = threadIdx.x;
  const int o = t & 127, h = t >> 7;
  const float bmax = sred[0], inv = 1.f / sred[1];
  float acc = 0.f;
  const int i0 = blk * 128;
  for (int i = i0 + h; i < i0 + 128; i += 2){
    float w = __expf(sc[i] - bmax) * inv;
    acc += w * Z[(size_t)i * 128 + o];
  }
  __shared__ float l[256];
  l[t] = acc;
  __syncthreads();
  if (h == 0) part[blk * 128 + o] = l[o] + l[o + 128];
}

__global__ __launch_bounds__(128) void final_red(
    const float* __restrict__ part, float* __restrict__ out){
  const int o = threadIdx.x;
  float s = 0.f;
  for (int b = 0; b < 64; ++b) s += part[b * 128 + o];
  out[o] = s;
}

// ---------------------------------------------------------------------------
extern "C" void kernel_launch(void* const* d_in, const int* in_sizes, int n_in,
                              void* d_out, int out_size, void* d_ws, size_t ws_size,
                              hipStream_t stream){
  const float* x  = (const float*)d_in[0];
  const float* A  = (const float*)d_in[1];
  const float* W1 = (const float*)d_in[2];
  const float* W2 = (const float*)d_in[3];
  const float* W3 = (const float*)d_in[4];
  const float* Wl = (const float*)d_in[5];
  const float* bl = (const float*)d_in[6];
  const float* q  = (const float*)d_in[7];
  const float* b  = (const float*)d_in[8];
  float* out = (float*)d_out;
  char* ws = (char*)d_ws;

  u16*   AB   = (u16*)(ws);                      // 128 MiB
  float* DS   = (float*)(ws + 134217728);        // 32 KiB
  u16*   VT   = (u16*)(ws + 134250496);          // 4 MiB [F][8192]
  u16*   HB   = (u16*)(ws + 138444800);          // 4 MiB [8192][256]
  float* SC   = (float*)(ws + 142639104);        // 8192 f32 scores
  float* SP   = (float*)(ws + 142671872);        // 64*128 f32
  float* SRED = (float*)(ws + 142704640);        // {max, sumexp}

  rowsum_convert<<<8192, 256, 0, stream>>>(A, AB, DS);
  // layer 1
  small_gemm<128, 256, false><<<512, 256, 0, stream>>>(x, W1, DS, VT);
  gemm_pipe<256, true, false><<<256, 1024, 0, stream>>>(AB, VT, DS, HB, nullptr);
  // layer 2
  small_gemm<256, 256, true><<<512, 256, 0, stream>>>(HB, W2, DS, VT);
  gemm_pipe<256, true, false><<<256, 1024, 0, stream>>>(AB, VT, DS, HB, nullptr);
  // layer 3 -> z_context f32 straight into d_out
  small_gemm<256, 128, true><<<256, 256, 0, stream>>>(HB, W3, DS, VT);
  gemm_pipe<128, false, true><<<256, 1024, 0, stream>>>(AB, VT, DS, nullptr, out);
  // attention pooling
  attn_scores<<<512, 256, 0, stream>>>(out, Wl, bl, q, b, SC);
  softmax_red<<<1, 1024, 0, stream>>>(SC, SRED);
  weighted_part<<<64, 256, 0, stream>>>(SC, SRED, out, SP);
  final_red<<<1, 128, 0, stream>>>(SP, out + 8192 * 128);
}

// Round 8
// 397.598 us; speedup vs baseline: 1.8774x; 1.8481x over previous
//
#include <hip/hip_runtime.h>

typedef unsigned short u16;
typedef unsigned int   u32;
typedef __bf16 bf16x8 __attribute__((ext_vector_type(8)));
typedef float  f32x4  __attribute__((ext_vector_type(4)));
typedef float  f32x16 __attribute__((ext_vector_type(16)));

__device__ __forceinline__ u16 f2bf(float f){
  u32 u = __float_as_uint(f);
  u32 r = (u + 0x7FFFu + ((u >> 16) & 1u)) >> 16;   // RNE
  return (u16)r;
}

// Inline-asm load (survives hipcc's load-sinking). "=&v": dest must not
// alias the address pair (delayed write).
#define GLD(dst, p, OFF) \
  asm volatile("global_load_dwordx4 %0, %1, off offset:" OFF \
               : "=&v"(dst) : "v"(p))
#define WAITV(N) do { \
    asm volatile("s_waitcnt vmcnt(" N ")"); \
    __builtin_amdgcn_sched_barrier(0); \
  } while (0)

// ===========================================================================
// TILED OPERAND LAYOUT (the R8 fix):
// R1/R4/R5/R7 all plateaued at ~200us with MfmaUtil ~6.5%: per-lane
// K-contiguous fragments make every global_load_dwordx4 a 32-way gather
// (32 discontiguous 32B segments 16KB apart) -> ~32 cacheline transactions
// per instruction -> VMEM-transaction-throughput-bound.
// Fix: store operands fragment-tiled. Tile = 32 rows x 16 k = 1KB:
//   elem (row, k) -> tile (row>>5, k>>4), lane = (row&31)|(((k>>3)&1)<<5),
//   byte = tile*1024 + lane*16 + (k&7)*2
// A consumer load is then ONE contiguous 1KB block (lane*16B), coalesced.
// ===========================================================================

// ---------------------------------------------------------------------------
// Pass 1: row sums + f32->bf16 + transpose to tiled layout via LDS.
// 256 blocks (rg = 32-row group) x 1024 threads. Per chunk: 32 rows x 256 k.
// ---------------------------------------------------------------------------
__global__ __launch_bounds__(1024) void rowsum_tileA(
    const float* __restrict__ A, u16* __restrict__ Ab, float* __restrict__ ds){
  __shared__ u16 lt[8192];               // 16 tiles x 512 u16 = 16 KB
  const int t = threadIdx.x;
  const int r = t >> 5, q = t & 31;      // row 0..31, 32 threads/row
  const int rg = blockIdx.x;
  const float* ar = A + ((size_t)rg * 32 + r) * 8192;
  float s = 0.f;
  for (int ch = 0; ch < 32; ++ch){
    #pragma unroll
    for (int j = 0; j < 2; ++j){
      const int c4 = ch * 64 + j * 32 + q;           // float4 col index
      float4 v = ((const float4*)ar)[c4];
      s += (v.x + v.y) + (v.z + v.w);
      const int cl = (j * 32 + q) * 4;               // local col 0..255
      const int idx = (cl >> 4) * 512 + ((r | (((cl >> 3) & 1) << 5)) * 8) + (cl & 7);
      ushort4 o;
      o.x = f2bf(v.x); o.y = f2bf(v.y); o.z = f2bf(v.z); o.w = f2bf(v.w);
      *(ushort4*)(lt + idx) = o;
    }
    __syncthreads();
    uint4* dst = (uint4*)(Ab + ((size_t)rg * 512 + ch * 16) * 512);
    dst[t] = ((const uint4*)lt)[t];                  // linear 16KB, coalesced
    __syncthreads();
  }
  #pragma unroll
  for (int m = 16; m > 0; m >>= 1) s += __shfl_xor(s, m, 64);
  if (q == 0) ds[rg * 32 + r] = rsqrtf(s);
}

// ---------------------------------------------------------------------------
// Small feature GEMM: Vt tiles = bf16( ds[i] * sum_k in[i][k] * W[k][o] )
// Output in tiled layout: tile (o>>5, i>>4), fragment-native.
// ---------------------------------------------------------------------------
template<int K, int F, bool INBF16>
__global__ __launch_bounds__(256) void small_gemm(
    const void* __restrict__ inp, const float* __restrict__ W,
    const float* __restrict__ ds, u16* __restrict__ Vt){
  constexpr int G   = 256 / F;     // 1 (F=256) or 2 (F=128)
  constexpr int RPB = 16 * G;      // rows per block
  __shared__ float xs[RPB * K];
  const int t  = threadIdx.x;
  const int r0 = blockIdx.x * RPB;
  if constexpr (INBF16){
    const u16* ip = (const u16*)inp + (size_t)r0 * K;
    constexpr int IT = (RPB * K) / (256 * 8);
    #pragma unroll
    for (int j = 0; j < IT; ++j){
      int c = j * 256 + t;
      uint4 v = ((const uint4*)ip)[c];
      float* xp = xs + c * 8;
      xp[0] = __uint_as_float((v.x & 0xFFFFu) << 16);
      xp[1] = __uint_as_float(v.x & 0xFFFF0000u);
      xp[2] = __uint_as_float((v.y & 0xFFFFu) << 16);
      xp[3] = __uint_as_float(v.y & 0xFFFF0000u);
      xp[4] = __uint_as_float((v.z & 0xFFFFu) << 16);
      xp[5] = __uint_as_float(v.z & 0xFFFF0000u);
      xp[6] = __uint_as_float((v.w & 0xFFFFu) << 16);
      xp[7] = __uint_as_float(v.w & 0xFFFF0000u);
    }
  } else {
    const float* ip = (const float*)inp + (size_t)r0 * K;
    constexpr int IT = (RPB * K) / (256 * 4);
    #pragma unroll
    for (int j = 0; j < IT; ++j){
      int c = j * 256 + t;
      ((float4*)xs)[c] = ((const float4*)ip)[c];
    }
  }
  __syncthreads();
  const int o = t % F, g = t / F;
  float acc[16];
  #pragma unroll
  for (int r = 0; r < 16; ++r) acc[r] = 0.f;
  const float* xr = xs + g * 16 * K;
  for (int k = 0; k < K; k += 4){
    float w0 = W[(k+0)*F + o];
    float w1 = W[(k+1)*F + o];
    float w2 = W[(k+2)*F + o];
    float w3 = W[(k+3)*F + o];
    #pragma unroll
    for (int r = 0; r < 16; ++r){
      float4 xv = *(const float4*)(xr + r*K + k);
      acc[r] += xv.x*w0 + xv.y*w1 + xv.z*w2 + xv.w*w3;
    }
  }
  const int rb = r0 + g * 16;              // 16-aligned -> one k-tile
  union { u16 u[16]; uint4 v[2]; } pk;
  #pragma unroll
  for (int r = 0; r < 16; ++r) pk.u[r] = f2bf(acc[r] * ds[rb + r]);
  // tiled store: tile (o>>5, rb>>4); lanes (o&31) [k-lo] and 32|(o&31) [k-hi]
  const size_t tile = ((size_t)(o >> 5) * 512 + (rb >> 4)) * 512;
  uint4* dst = (uint4*)(Vt + tile + (size_t)(o & 31) * 8);
  dst[0]  = pk.v[0];
  dst[32] = pk.v[1];
}

// ---------------------------------------------------------------------------
// Big GEMM: in-block K-split, inline-asm pipelined K-loop on TILED operands,
// LDS tree reduce.  out[i][o] = ds[i]*sum_j Ab[i][j]*Vt[o][j]
// 256 blocks x 1024 threads = 16 waves = 4 K-splits x 4 col-groups.
// Every load = contiguous 1KB tile fragment (lane*16B). Counted vmcnt(9/6).
// ---------------------------------------------------------------------------
template<int F, bool RELU, bool OUTF32>
__global__ __launch_bounds__(1024, 4) void gemm_pipe(
    const u16* __restrict__ Ab, const u16* __restrict__ Vt,
    const float* __restrict__ ds, u16* __restrict__ Hout, float* __restrict__ Fout){
  constexpr int CT  = F / 128;          // 32-col tiles per wave (2 or 1)
  __shared__ float red[2][32][F];       // 64 KB (F=256) / 32 KB (F=128)

  const int t = threadIdx.x, wave = t >> 6, lane = t & 63;
  const int ks = wave >> 2;             // K-split 0..3
  const int cg = wave & 3;              // col-group 0..3
  const int row0 = blockIdx.x * 32;
  const int colb = cg * (F / 4);

  // tiled pointers: tile stride = 512 elems (1KB); ks slice = 128 tiles
  const u16* pa = Ab + ((size_t)blockIdx.x * 512 + ks * 128) * 512 + lane * 8;

  f32x16 acc0, acc1;
  #pragma unroll
  for (int i = 0; i < 16; ++i){ acc0[i] = 0.f; acc1[i] = 0.f; }

  if constexpr (CT == 2){
    const u16* pb0 = Vt + ((size_t)(cg * 2)     * 512 + ks * 128) * 512 + lane * 8;
    const u16* pb1 = Vt + ((size_t)(cg * 2 + 1) * 512 + ks * 128) * 512 + lane * 8;
    bf16x8 aQ[4], b0Q[4], b1Q[4];
    GLD(aQ[0],pa,"0");    GLD(b0Q[0],pb0,"0");    GLD(b1Q[0],pb1,"0");
    GLD(aQ[1],pa,"1024"); GLD(b0Q[1],pb0,"1024"); GLD(b1Q[1],pb1,"1024");
    GLD(aQ[2],pa,"2048"); GLD(b0Q[2],pb0,"2048"); GLD(b1Q[2],pb1,"2048");
    GLD(aQ[3],pa,"3072"); GLD(b0Q[3],pb0,"3072"); GLD(b1Q[3],pb1,"3072");
    pa += 2048; pb0 += 2048; pb1 += 2048;
    #define STEP2(U, OFF) \
      WAITV("9"); \
      acc0 = __builtin_amdgcn_mfma_f32_32x32x16_bf16(aQ[U], b0Q[U], acc0, 0, 0, 0); \
      acc1 = __builtin_amdgcn_mfma_f32_32x32x16_bf16(aQ[U], b1Q[U], acc1, 0, 0, 0); \
      GLD(aQ[U],pa,OFF); GLD(b0Q[U],pb0,OFF); GLD(b1Q[U],pb1,OFF)
    for (int it = 0; it < 31; ++it){
      STEP2(0, "0");
      STEP2(1, "1024");
      STEP2(2, "2048");
      STEP2(3, "3072");
      pa += 2048; pb0 += 2048; pb1 += 2048;
    }
    #undef STEP2
    WAITV("9");
    acc0 = __builtin_amdgcn_mfma_f32_32x32x16_bf16(aQ[0], b0Q[0], acc0, 0, 0, 0);
    acc1 = __builtin_amdgcn_mfma_f32_32x32x16_bf16(aQ[0], b1Q[0], acc1, 0, 0, 0);
    WAITV("6");
    acc0 = __builtin_amdgcn_mfma_f32_32x32x16_bf16(aQ[1], b0Q[1], acc0, 0, 0, 0);
    acc1 = __builtin_amdgcn_mfma_f32_32x32x16_bf16(aQ[1], b1Q[1], acc1, 0, 0, 0);
    WAITV("3");
    acc0 = __builtin_amdgcn_mfma_f32_32x32x16_bf16(aQ[2], b0Q[2], acc0, 0, 0, 0);
    acc1 = __builtin_amdgcn_mfma_f32_32x32x16_bf16(aQ[2], b1Q[2], acc1, 0, 0, 0);
    WAITV("0");
    acc0 = __builtin_amdgcn_mfma_f32_32x32x16_bf16(aQ[3], b0Q[3], acc0, 0, 0, 0);
    acc1 = __builtin_amdgcn_mfma_f32_32x32x16_bf16(aQ[3], b1Q[3], acc1, 0, 0, 0);
  } else {
    const u16* pb0 = Vt + ((size_t)cg * 512 + ks * 128) * 512 + lane * 8;
    bf16x8 aQ[4], b0Q[4];
    GLD(aQ[0],pa,"0");    GLD(b0Q[0],pb0,"0");
    GLD(aQ[1],pa,"1024"); GLD(b0Q[1],pb0,"1024");
    GLD(aQ[2],pa,"2048"); GLD(b0Q[2],pb0,"2048");
    GLD(aQ[3],pa,"3072"); GLD(b0Q[3],pb0,"3072");
    pa += 2048; pb0 += 2048;
    #define STEP1(U, OFF) \
      WAITV("6"); \
      acc0 = __builtin_amdgcn_mfma_f32_32x32x16_bf16(aQ[U], b0Q[U], acc0, 0, 0, 0); \
      GLD(aQ[U],pa,OFF); GLD(b0Q[U],pb0,OFF)
    for (int it = 0; it < 31; ++it){
      STEP1(0, "0");
      STEP1(1, "1024");
      STEP1(2, "2048");
      STEP1(3, "3072");
      pa += 2048; pb0 += 2048;
    }
    #undef STEP1
    WAITV("6");
    acc0 = __builtin_amdgcn_mfma_f32_32x32x16_bf16(aQ[0], b0Q[0], acc0, 0, 0, 0);
    WAITV("4");
    acc0 = __builtin_amdgcn_mfma_f32_32x32x16_bf16(aQ[1], b0Q[1], acc0, 0, 0, 0);
    WAITV("2");
    acc0 = __builtin_amdgcn_mfma_f32_32x32x16_bf16(aQ[2], b0Q[2], acc0, 0, 0, 0);
    WAITV("0");
    acc0 = __builtin_amdgcn_mfma_f32_32x32x16_bf16(aQ[3], b0Q[3], acc0, 0, 0, 0);
  }

  // ---- K-split tree reduction: ((ks0+ks2)+(ks1+ks3)), 3 barriers total ----
  // C/D layout (m74/m101): col = lane&31, row = (r&3) + 8*(r>>2) + 4*(lane>>5)
  const int rhi = (lane >> 5) << 2;
  const int cl  = lane & 31;
  f32x16 accv[2];
  accv[0] = acc0; accv[1] = acc1;
  if (ks >= 2){
    #pragma unroll
    for (int ct = 0; ct < CT; ++ct)
      #pragma unroll
      for (int r = 0; r < 16; ++r)
        red[ks - 2][(r & 3) + ((r >> 2) << 3) + rhi][colb + ct * 32 + cl] = accv[ct][r];
  }
  __syncthreads();
  if (ks < 2){
    #pragma unroll
    for (int ct = 0; ct < CT; ++ct)
      #pragma unroll
      for (int r = 0; r < 16; ++r)
        accv[ct][r] += red[ks][(r & 3) + ((r >> 2) << 3) + rhi][colb + ct * 32 + cl];
  }
  __syncthreads();
  if (ks == 1){
    #pragma unroll
    for (int ct = 0; ct < CT; ++ct)
      #pragma unroll
      for (int r = 0; r < 16; ++r)
        red[0][(r & 3) + ((r >> 2) << 3) + rhi][colb + ct * 32 + cl] = accv[ct][r];
  }
  __syncthreads();
  if (ks == 0){
    #pragma unroll
    for (int ct = 0; ct < CT; ++ct){
      #pragma unroll
      for (int r = 0; r < 16; ++r){
        const int rl = (r & 3) + ((r >> 2) << 3) + rhi;
        float v = accv[ct][r] + red[0][rl][colb + ct * 32 + cl];
        const int row = row0 + rl;
        v *= ds[row];
        if (RELU) v = fmaxf(v, 0.f);
        const int col = colb + ct * 32 + cl;
        if (OUTF32) Fout[(size_t)row * F + col] = v;
        else        Hout[(size_t)row * F + col] = f2bf(v);
      }
    }
  }
}

// ---------------------------------------------------------------------------
// Attention scores: sc[i] = tanh(Z[i,:] @ Wl^T + bl) @ q + b
// ---------------------------------------------------------------------------
__device__ __forceinline__ float tanh_fast(float x){
  x = fminf(fmaxf(x, -15.f), 15.f);
  float e = __expf(2.f * x);
  return (e - 1.f) / (e + 1.f);
}

__global__ __launch_bounds__(256) void attn_scores(
    const float* __restrict__ Z, const float* __restrict__ Wl,
    const float* __restrict__ bl, const float* __restrict__ q,
    const float* __restrict__ bsc, float* __restrict__ sc){
  __shared__ float wl[128 * 128];          // 64 KiB exactly, swizzled
  const int t = threadIdx.x, lane = t & 63, wave = t >> 6;
  for (int j = 0; j < 64; ++j){
    int idx = j * 256 + t;
    int o = idx >> 7, k = idx & 127;
    int c = k >> 2, e = k & 3;
    wl[o * 128 + (((c ^ (o & 31)) << 2) | e)] = Wl[idx];
  }
  __syncthreads();
  const float bl0 = bl[lane], bl1 = bl[lane + 64];
  const float q0  = q[lane],  q1  = q[lane + 64];
  const float bb  = bsc[0];
  const int r0 = blockIdx.x * 16;
  for (int rr = 0; rr < 4; ++rr){
    int r = r0 + wave * 4 + rr;
    float d0 = 0.f, d1 = 0.f;
    #pragma unroll
    for (int c = 0; c < 32; ++c){
      float4 zv = *(const float4*)(Z + (size_t)r * 128 + c * 4);
      float4 w0 = *(const float4*)&wl[ lane      * 128 + ((c ^ (lane & 31)) << 2)];
      float4 w1 = *(const float4*)&wl[(lane + 64)* 128 + ((c ^ (lane & 31)) << 2)];
      d0 += zv.x*w0.x + zv.y*w0.y + zv.z*w0.z + zv.w*w0.w;
      d1 += zv.x*w1.x + zv.y*w1.y + zv.z*w1.z + zv.w*w1.w;
    }
    float s = tanh_fast(d0 + bl0) * q0 + tanh_fast(d1 + bl1) * q1;
    #pragma unroll
    for (int off = 32; off > 0; off >>= 1) s += __shfl_down(s, off, 64);
    if (lane == 0) sc[r] = s + bb;
  }
}

__global__ __launch_bounds__(1024) void softmax_red(
    const float* __restrict__ sc, float* __restrict__ sred){
  const int t = threadIdx.x, lane = t & 63, wave = t >> 6;
  __shared__ float red[16];
  float m = -1e30f;
  for (int i = t; i < 8192; i += 1024) m = fmaxf(m, sc[i]);
  #pragma unroll
  for (int off = 32; off > 0; off >>= 1) m = fmaxf(m, __shfl_down(m, off, 64));
  if (lane == 0) red[wave] = m;
  __syncthreads();
  if (t == 0){
    float mm = red[0];
    for (int w = 1; w < 16; ++w) mm = fmaxf(mm, red[w]);
    red[0] = mm;
  }
  __syncthreads();
  const float bmax = red[0];
  __syncthreads();
  float s = 0.f;
  for (int i = t; i < 8192; i += 1024) s += __expf(sc[i] - bmax);
  #pragma unroll
  for (int off = 32; off > 0; off >>= 1) s += __shfl_down(s, off, 64);
  if (lane == 0) red[wave] = s;
  __syncthreads();
  if (t == 0){
    float ss = 0.f;
    for (int w = 0; w < 16; ++w) ss += red[w];
    sred[0] = bmax; sred[1] = ss;
  }
}

__global__ __launch_bounds__(256) void weighted_part(
    const float* __restrict__ sc, const float* __restrict__ sred,
    const float* __restrict__ Z, float* __restrict__ part){
  const int blk = blockIdx.x, t = threadIdx.x;
  const int o = t & 127, h = t >> 7;
  const float bmax = sred[0], inv = 1.f / sred[1];
  float acc = 0.f;
  const int i0 = blk * 128;
  for (int i = i0 + h; i < i0 + 128; i += 2){
    float w = __expf(sc[i] - bmax) * inv;
    acc += w * Z[(size_t)i * 128 + o];
  }
  __shared__ float l[256];
  l[t] = acc;
  __syncthreads();
  if (h == 0) part[blk * 128 + o] = l[o] + l[o + 128];
}

__global__ __launch_bounds__(128) void final_red(
    const float* __restrict__ part, float* __restrict__ out){
  const int o = threadIdx.x;
  float s = 0.f;
  for (int b = 0; b < 64; ++b) s += part[b * 128 + o];
  out[o] = s;
}

// ---------------------------------------------------------------------------
extern "C" void kernel_launch(void* const* d_in, const int* in_sizes, int n_in,
                              void* d_out, int out_size, void* d_ws, size_t ws_size,
                              hipStream_t stream){
  const float* x  = (const float*)d_in[0];
  const float* A  = (const float*)d_in[1];
  const float* W1 = (const float*)d_in[2];
  const float* W2 = (const float*)d_in[3];
  const float* W3 = (const float*)d_in[4];
  const float* Wl = (const float*)d_in[5];
  const float* bl = (const float*)d_in[6];
  const float* q  = (const float*)d_in[7];
  const float* b  = (const float*)d_in[8];
  float* out = (float*)d_out;
  char* ws = (char*)d_ws;

  u16*   AB   = (u16*)(ws);                      // 128 MiB, tiled
  float* DS   = (float*)(ws + 134217728);        // 32 KiB
  u16*   VT   = (u16*)(ws + 134250496);          // 4 MiB, tiled
  u16*   HB   = (u16*)(ws + 138444800);          // 4 MiB [8192][256] row-major
  float* SC   = (float*)(ws + 142639104);        // 8192 f32 scores
  float* SP   = (float*)(ws + 142671872);        // 64*128 f32
  float* SRED = (float*)(ws + 142704640);        // {max, sumexp}

  rowsum_tileA<<<256, 1024, 0, stream>>>(A, AB, DS);
  // layer 1
  small_gemm<128, 256, false><<<512, 256, 0, stream>>>(x, W1, DS, VT);
  gemm_pipe<256, true, false><<<256, 1024, 0, stream>>>(AB, VT, DS, HB, nullptr);
  // layer 2
  small_gemm<256, 256, true><<<512, 256, 0, stream>>>(HB, W2, DS, VT);
  gemm_pipe<256, true, false><<<256, 1024, 0, stream>>>(AB, VT, DS, HB, nullptr);
  // layer 3 -> z_context f32 straight into d_out
  small_gemm<256, 128, true><<<256, 256, 0, stream>>>(HB, W3, DS, VT);
  gemm_pipe<128, false, true><<<256, 1024, 0, stream>>>(AB, VT, DS, nullptr, out);
  // attention pooling
  attn_scores<<<512, 256, 0, stream>>>(out, Wl, bl, q, b, SC);
  softmax_red<<<1, 1024, 0, stream>>>(SC, SRED);
  weighted_part<<<64, 256, 0, stream>>>(SC, SRED, out, SP);
  final_red<<<1, 128, 0, stream>>>(SP, out + 8192 * 128);
}